// Round 3
// baseline (934.023 us; speedup 1.0000x reference)
//
#include <hip/hip_runtime.h>
#include <hip/hip_bf16.h>

#define NN   100000
#define NE   3200000
#define IND  512
#define NPB  256                 // nodes per bucket
#define NBKT 391                 // ceil(NN/NPB)
#define TILE 8192
#define NTILE 391                // ceil(NE/TILE)
#define NB_N 391                 // ceil(NN/256)

// ---------------- zero bucket counters ----------------
__global__ void k_zero(unsigned int* __restrict__ bcnt) {
    int i = threadIdx.x;
    if (i < NBKT) bcnt[i] = 0u;
}

// ---------------- per-bucket histogram (LDS-merged) ----------------
__global__ __launch_bounds__(256) void k_hist(const int* __restrict__ dst,
                                              unsigned int* __restrict__ bcnt) {
    __shared__ unsigned int h[NBKT];
    for (int i = threadIdx.x; i < NBKT; i += 256) h[i] = 0u;
    __syncthreads();
    int stride = gridDim.x * 256;
    for (int e = blockIdx.x * 256 + threadIdx.x; e < NE; e += stride)
        atomicAdd(&h[((unsigned)dst[e]) >> 8], 1u);
    __syncthreads();
    for (int i = threadIdx.x; i < NBKT; i += 256)
        if (h[i]) atomicAdd(&bcnt[i], h[i]);
}

// ---------------- scan bucket counts -> offsets + cursors ----------------
__global__ __launch_bounds__(512) void k_scan(const unsigned int* __restrict__ bcnt,
                                              unsigned int* __restrict__ boffs,
                                              unsigned int* __restrict__ cursor) {
    __shared__ unsigned int t[512];
    int i = threadIdx.x;
    unsigned int c = (i < NBKT) ? bcnt[i] : 0u;
    t[i] = c;
    __syncthreads();
    for (int o = 1; o < 512; o <<= 1) {
        unsigned int v = (i >= o) ? t[i - o] : 0u;
        __syncthreads();
        t[i] += v;
        __syncthreads();
    }
    if (i < NBKT) { unsigned int ex = t[i] - c; boffs[i] = ex; cursor[i] = ex; }
    if (i == 0) boffs[NBKT] = NE;
}

// ---------------- LDS-staged binning scatter: coalesced run writes ----------------
__global__ __launch_bounds__(512) void k_binscatter(const int* __restrict__ src,
                                                    const int* __restrict__ dst,
                                                    unsigned int* __restrict__ cursor,
                                                    unsigned int* __restrict__ recs) {
    __shared__ unsigned int   stage[TILE];     // 32 KB
    __shared__ unsigned short sbkt[TILE];      // 16 KB
    __shared__ unsigned int   thist[512];
    __shared__ unsigned int   tstart[512];
    __shared__ unsigned int   tcur[NBKT];
    __shared__ unsigned int   gbase[NBKT];
    const int tid = threadIdx.x;
    const int t0  = blockIdx.x * TILE;
    const int cnt = min(TILE, NE - t0);

    thist[tid] = 0u;
    __syncthreads();

    unsigned int rec[16], bk[16];
#pragma unroll
    for (int k = 0; k < 16; ++k) {
        int i = tid + k * 512;
        if (i < cnt) {
            unsigned int d = (unsigned)dst[t0 + i];
            unsigned int s = (unsigned)src[t0 + i];
            unsigned int b = d >> 8;
            rec[k] = ((d & 255u) << 17) | s;
            bk[k]  = b;
            atomicAdd(&thist[b], 1u);
        } else bk[k] = 0xFFFFFFFFu;
    }
    __syncthreads();

    // exclusive scan of thist -> tstart
    unsigned int v = thist[tid];
    tstart[tid] = v;
    __syncthreads();
    for (int o = 1; o < 512; o <<= 1) {
        unsigned int u = (tid >= o) ? tstart[tid - o] : 0u;
        __syncthreads();
        tstart[tid] += u;
        __syncthreads();
    }
    tstart[tid] -= v;                      // own slot only: safe
    __syncthreads();

    if (tid < NBKT) {
        unsigned int cb = thist[tid];
        tcur[tid] = tstart[tid];
        if (cb) gbase[tid] = atomicAdd(&cursor[tid], cb);
    }
    __syncthreads();

#pragma unroll
    for (int k = 0; k < 16; ++k) {
        if (bk[k] != 0xFFFFFFFFu) {
            unsigned int p = atomicAdd(&tcur[bk[k]], 1u);
            stage[p] = rec[k];
            sbkt[p]  = (unsigned short)bk[k];
        }
    }
    __syncthreads();

    for (int i = tid; i < cnt; i += 512) {
        unsigned int b = sbkt[i];
        recs[gbase[b] + (i - tstart[b])] = stage[i];   // runs of ~21 recs: coalesced
    }
}

// ---------------- degree/dinv from bins ----------------
__global__ __launch_bounds__(256) void k_degbin(const unsigned int* __restrict__ boffs,
                                                const unsigned int* __restrict__ recs,
                                                float* __restrict__ dinv) {
    __shared__ unsigned int cnt[NPB];
    const int b = blockIdx.x;
    cnt[threadIdx.x] = 0u;
    __syncthreads();
    const unsigned int beg = boffs[b], end = boffs[b + 1];
    for (unsigned int i = beg + threadIdx.x; i < end; i += 256)
        atomicAdd(&cnt[recs[i] >> 17], 1u);
    __syncthreads();
    int n = b * NPB + threadIdx.x;
    if (n < NN) dinv[n] = rsqrtf((float)(cnt[threadIdx.x] + 1u));
}

// ---------------- layer-1 GEMM: h1 = x @ W1 ----------------
__global__ __launch_bounds__(256) void k_gemm1(
    const float* __restrict__ x, const float* __restrict__ W1,
    float* __restrict__ h1) {
    __shared__ float Xs[256 * 33];
    const int tid = threadIdx.x;
    const int n0  = blockIdx.x * 256;
    const int n   = n0 + tid;

    float acc[16];
#pragma unroll
    for (int j = 0; j < 16; ++j) acc[j] = 0.f;

    for (int kc = 0; kc < IND; kc += 32) {
        __syncthreads();
#pragma unroll
        for (int r = 0; r < 8; ++r) {
            int flat = r * 256 + tid;
            int row  = flat >> 3;
            int col  = (flat & 7) << 2;
            int gn   = n0 + row;
            if (gn < NN) {
                const float4 vv = *(const float4*)(x + (size_t)gn * IND + kc + col);
                float* d = &Xs[row * 33 + col];
                d[0] = vv.x; d[1] = vv.y; d[2] = vv.z; d[3] = vv.w;
            }
        }
        __syncthreads();
        if (n < NN) {
#pragma unroll
            for (int i = 0; i < 32; ++i) {
                float xv = Xs[tid * 33 + i];
                const float* wr = W1 + (size_t)(kc + i) * 16;   // wave-uniform -> s_load
#pragma unroll
                for (int j = 0; j < 16; ++j) acc[j] = fmaf(xv, wr[j], acc[j]);
            }
        }
    }
    if (n < NN) {
#pragma unroll
        for (int j = 0; j < 16; j += 4)
            *(float4*)(h1 + (size_t)n * 16 + j) =
                make_float4(acc[j], acc[j+1], acc[j+2], acc[j+3]);
    }
}

// ---------------- binned aggregation L1 + relu/b1 + W2 -> h2 ----------------
// one block per bucket; agg in LDS; 32 groups x 16 lanes
__global__ __launch_bounds__(512) void k_agg1(
    const unsigned int* __restrict__ boffs, const unsigned int* __restrict__ recs,
    const float* __restrict__ dinv, const float* __restrict__ h1,
    const float* __restrict__ b1, const float* __restrict__ W2,
    float* __restrict__ h2) {
    __shared__ float agg[NPB * 16];   // 16 KB
    __shared__ float dloc[NPB];
    const int b = blockIdx.x, tid = threadIdx.x;
    const int n0 = b * NPB;

    for (int i = tid; i < NPB; i += 512) dloc[i] = (n0 + i < NN) ? dinv[n0 + i] : 0.f;
    __syncthreads();
    for (int i = tid; i < NPB * 16; i += 512) {
        int ln = i >> 4, n = n0 + ln;
        float v = (n < NN) ? h1[(size_t)n * 16 + (i & 15)] : 0.f;
        float di = dloc[ln];
        agg[i] = v * di * di;          // self-loop
    }
    __syncthreads();

    const unsigned int beg = boffs[b], end = boffs[b + 1];
    const int g = tid >> 4, j = tid & 15;
    unsigned int e = beg + g;
    for (; e + 32 < end; e += 64) {    // unroll 2: independent load chains
        unsigned int r0 = recs[e], r1 = recs[e + 32];
        unsigned int s0 = r0 & 0x1FFFFu, s1 = r1 & 0x1FFFFu;
        unsigned int d0 = r0 >> 17,      d1 = r1 >> 17;
        float w0 = dinv[s0] * dloc[d0], w1 = dinv[s1] * dloc[d1];
        float v0 = h1[(size_t)s0 * 16 + j], v1 = h1[(size_t)s1 * 16 + j];
        unsafeAtomicAdd(&agg[d0 * 16 + j], v0 * w0);
        unsafeAtomicAdd(&agg[d1 * 16 + j], v1 * w1);
    }
    if (e < end) {
        unsigned int r = recs[e];
        unsigned int s = r & 0x1FFFFu, d = r >> 17;
        unsafeAtomicAdd(&agg[d * 16 + j], h1[(size_t)s * 16 + j] * dinv[s] * dloc[d]);
    }
    __syncthreads();

    for (int i = tid; i < NPB * 16; i += 512) agg[i] = fmaxf(agg[i] + b1[i & 15], 0.f);
    __syncthreads();
    for (int i = tid; i < NPB * 8; i += 512) {
        int ln = i >> 3, jj = i & 7, n = n0 + ln;
        if (n >= NN) continue;
        float o = 0.f;
        if (jj < 7) {
#pragma unroll
            for (int k = 0; k < 16; ++k) o = fmaf(agg[ln * 16 + k], W2[k * 7 + jj], o);
        }
        h2[(size_t)n * 8 + jj] = o;
    }
}

// ---------------- binned aggregation L2 + b2 + log_softmax -> out ----------------
// 64 groups x 8 lanes
__global__ __launch_bounds__(512) void k_agg2(
    const unsigned int* __restrict__ boffs, const unsigned int* __restrict__ recs,
    const float* __restrict__ dinv, const float* __restrict__ h2,
    const float* __restrict__ b2, float* __restrict__ out) {
    __shared__ float agg[NPB * 8];    // 8 KB
    __shared__ float dloc[NPB];
    const int b = blockIdx.x, tid = threadIdx.x;
    const int n0 = b * NPB;

    for (int i = tid; i < NPB; i += 512) dloc[i] = (n0 + i < NN) ? dinv[n0 + i] : 0.f;
    __syncthreads();
    for (int i = tid; i < NPB * 8; i += 512) {
        int ln = i >> 3, n = n0 + ln;
        float v = (n < NN) ? h2[(size_t)n * 8 + (i & 7)] : 0.f;
        float di = dloc[ln];
        agg[i] = v * di * di;          // self-loop
    }
    __syncthreads();

    const unsigned int beg = boffs[b], end = boffs[b + 1];
    const int g = tid >> 3, j = tid & 7;
    unsigned int e = beg + g;
    for (; e + 64 < end; e += 128) {
        unsigned int r0 = recs[e], r1 = recs[e + 64];
        unsigned int s0 = r0 & 0x1FFFFu, s1 = r1 & 0x1FFFFu;
        unsigned int d0 = r0 >> 17,      d1 = r1 >> 17;
        float w0 = dinv[s0] * dloc[d0], w1 = dinv[s1] * dloc[d1];
        float v0 = h2[(size_t)s0 * 8 + j], v1 = h2[(size_t)s1 * 8 + j];
        unsafeAtomicAdd(&agg[d0 * 8 + j], v0 * w0);
        unsafeAtomicAdd(&agg[d1 * 8 + j], v1 * w1);
    }
    if (e < end) {
        unsigned int r = recs[e];
        unsigned int s = r & 0x1FFFFu, d = r >> 17;
        unsafeAtomicAdd(&agg[d * 8 + j], h2[(size_t)s * 8 + j] * dinv[s] * dloc[d]);
    }
    __syncthreads();

    for (int ln = tid; ln < NPB; ln += 512) {
        int n = n0 + ln;
        if (n >= NN) continue;
        float v[7]; float m = -1e30f;
#pragma unroll
        for (int jj = 0; jj < 7; ++jj) { v[jj] = agg[ln * 8 + jj] + b2[jj]; m = fmaxf(m, v[jj]); }
        float s = 0.f;
#pragma unroll
        for (int jj = 0; jj < 7; ++jj) s += expf(v[jj] - m);
        float ls = logf(s) + m;
#pragma unroll
        for (int jj = 0; jj < 7; ++jj) out[(size_t)n * 7 + jj] = v[jj] - ls;
    }
}

extern "C" void kernel_launch(void* const* d_in, const int* in_sizes, int n_in,
                              void* d_out, int out_size, void* d_ws, size_t ws_size,
                              hipStream_t stream) {
    const float* x  = (const float*)d_in[0];
    const int*   ei = (const int*)d_in[1];
    const float* W1 = (const float*)d_in[2];
    const float* b1 = (const float*)d_in[3];
    const float* W2 = (const float*)d_in[4];
    const float* b2 = (const float*)d_in[5];
    float* out = (float*)d_out;

    const int* src = ei;
    const int* dst = ei + NE;

    char* ws = (char*)d_ws;
    size_t o = 0;
    auto alloc = [&](size_t bytes) -> void* {
        void* p = ws + o;
        o = (o + bytes + 255) & ~(size_t)255;
        return p;
    };
    unsigned int* bcnt   = (unsigned int*)alloc((size_t)NBKT * 4);
    unsigned int* boffs  = (unsigned int*)alloc((size_t)(NBKT + 1) * 4);
    unsigned int* cursor = (unsigned int*)alloc((size_t)NBKT * 4);
    unsigned int* recs   = (unsigned int*)alloc((size_t)NE * 4);
    float*        dinv   = (float*)alloc((size_t)NN * 4);
    float*        h1     = (float*)alloc((size_t)NN * 16 * 4);
    float*        h2     = (float*)alloc((size_t)NN * 8 * 4);

    k_zero      <<<1, 512, 0, stream>>>(bcnt);
    k_hist      <<<512, 256, 0, stream>>>(dst, bcnt);
    k_scan      <<<1, 512, 0, stream>>>(bcnt, boffs, cursor);
    k_binscatter<<<NTILE, 512, 0, stream>>>(src, dst, cursor, recs);
    k_degbin    <<<NBKT, 256, 0, stream>>>(boffs, recs, dinv);
    k_gemm1     <<<NB_N, 256, 0, stream>>>(x, W1, h1);
    k_agg1      <<<NBKT, 512, 0, stream>>>(boffs, recs, dinv, h1, b1, W2, h2);
    k_agg2      <<<NBKT, 512, 0, stream>>>(boffs, recs, dinv, h2, b2, out);
}

// Round 4
// 931.503 us; speedup vs baseline: 1.0027x; 1.0027x over previous
//
#include <hip/hip_runtime.h>
#include <hip/hip_bf16.h>

#define NN   100000
#define NE   3200000
#define IND  512
#define NPB  256                 // nodes per bucket
#define NBKT 391                 // ceil(NN/NPB)
#define TILE 8192
#define NTILE 391                // ceil(NE/TILE)
#define NB_N 391                 // ceil(NN/256)

// ---------------- zero bucket counters ----------------
__global__ void k_zero(unsigned int* __restrict__ bcnt) {
    int i = threadIdx.x;
    if (i < NBKT) bcnt[i] = 0u;
}

// ---------------- per-bucket histogram (LDS-merged) ----------------
__global__ __launch_bounds__(256) void k_hist(const int* __restrict__ dst,
                                              unsigned int* __restrict__ bcnt) {
    __shared__ unsigned int h[NBKT];
    for (int i = threadIdx.x; i < NBKT; i += 256) h[i] = 0u;
    __syncthreads();
    int stride = gridDim.x * 256;
    for (int e = blockIdx.x * 256 + threadIdx.x; e < NE; e += stride)
        atomicAdd(&h[((unsigned)dst[e]) >> 8], 1u);
    __syncthreads();
    for (int i = threadIdx.x; i < NBKT; i += 256)
        if (h[i]) atomicAdd(&bcnt[i], h[i]);
}

// ---------------- scan bucket counts -> offsets + cursors ----------------
__global__ __launch_bounds__(512) void k_scan(const unsigned int* __restrict__ bcnt,
                                              unsigned int* __restrict__ boffs,
                                              unsigned int* __restrict__ cursor) {
    __shared__ unsigned int t[512];
    int i = threadIdx.x;
    unsigned int c = (i < NBKT) ? bcnt[i] : 0u;
    t[i] = c;
    __syncthreads();
    for (int o = 1; o < 512; o <<= 1) {
        unsigned int v = (i >= o) ? t[i - o] : 0u;
        __syncthreads();
        t[i] += v;
        __syncthreads();
    }
    if (i < NBKT) { unsigned int ex = t[i] - c; boffs[i] = ex; cursor[i] = ex; }
    if (i == 0) boffs[NBKT] = NE;
}

// ---------------- LDS-staged binning scatter: coalesced run writes ----------------
__global__ __launch_bounds__(512) void k_binscatter(const int* __restrict__ src,
                                                    const int* __restrict__ dst,
                                                    unsigned int* __restrict__ cursor,
                                                    unsigned int* __restrict__ recs) {
    __shared__ unsigned int   stage[TILE];     // 32 KB
    __shared__ unsigned short sbkt[TILE];      // 16 KB
    __shared__ unsigned int   thist[512];
    __shared__ unsigned int   tstart[512];
    __shared__ unsigned int   tcur[NBKT];
    __shared__ unsigned int   gbase[NBKT];
    const int tid = threadIdx.x;
    const int t0  = blockIdx.x * TILE;
    const int cnt = min(TILE, NE - t0);

    thist[tid] = 0u;
    __syncthreads();

    unsigned int rec[16], bk[16];
#pragma unroll
    for (int k = 0; k < 16; ++k) {
        int i = tid + k * 512;
        if (i < cnt) {
            unsigned int d = (unsigned)dst[t0 + i];
            unsigned int s = (unsigned)src[t0 + i];
            unsigned int b = d >> 8;
            rec[k] = ((d & 255u) << 17) | s;
            bk[k]  = b;
            atomicAdd(&thist[b], 1u);
        } else bk[k] = 0xFFFFFFFFu;
    }
    __syncthreads();

    // exclusive scan of thist -> tstart
    unsigned int v = thist[tid];
    tstart[tid] = v;
    __syncthreads();
    for (int o = 1; o < 512; o <<= 1) {
        unsigned int u = (tid >= o) ? tstart[tid - o] : 0u;
        __syncthreads();
        tstart[tid] += u;
        __syncthreads();
    }
    tstart[tid] -= v;
    __syncthreads();

    if (tid < NBKT) {
        unsigned int cb = thist[tid];
        tcur[tid] = tstart[tid];
        if (cb) gbase[tid] = atomicAdd(&cursor[tid], cb);
    }
    __syncthreads();

#pragma unroll
    for (int k = 0; k < 16; ++k) {
        if (bk[k] != 0xFFFFFFFFu) {
            unsigned int p = atomicAdd(&tcur[bk[k]], 1u);
            stage[p] = rec[k];
            sbkt[p]  = (unsigned short)bk[k];
        }
    }
    __syncthreads();

    for (int i = tid; i < cnt; i += 512) {
        unsigned int b = sbkt[i];
        recs[gbase[b] + (i - tstart[b])] = stage[i];
    }
}

// ---------------- degree/dinv from bins ----------------
__global__ __launch_bounds__(256) void k_degbin(const unsigned int* __restrict__ boffs,
                                                const unsigned int* __restrict__ recs,
                                                float* __restrict__ dinv) {
    __shared__ unsigned int cnt[NPB];
    const int b = blockIdx.x;
    cnt[threadIdx.x] = 0u;
    __syncthreads();
    const unsigned int beg = boffs[b], end = boffs[b + 1];
    for (unsigned int i = beg + threadIdx.x; i < end; i += 256)
        atomicAdd(&cnt[recs[i] >> 17], 1u);
    __syncthreads();
    int n = b * NPB + threadIdx.x;
    if (n < NN) dinv[n] = rsqrtf((float)(cnt[threadIdx.x] + 1u));
}

// ---------------- layer-1 GEMM: h1s = (x @ W1) * dinv[n]  (pre-scaled by src dinv) ----------------
__global__ __launch_bounds__(256) void k_gemm1(
    const float* __restrict__ x, const float* __restrict__ W1,
    const float* __restrict__ dinv, float* __restrict__ h1s) {
    __shared__ float Xs[256 * 33];
    const int tid = threadIdx.x;
    const int n0  = blockIdx.x * 256;
    const int n   = n0 + tid;

    float acc[16];
#pragma unroll
    for (int j = 0; j < 16; ++j) acc[j] = 0.f;

    for (int kc = 0; kc < IND; kc += 32) {
        __syncthreads();
#pragma unroll
        for (int r = 0; r < 8; ++r) {
            int flat = r * 256 + tid;
            int row  = flat >> 3;
            int col  = (flat & 7) << 2;
            int gn   = n0 + row;
            if (gn < NN) {
                const float4 vv = *(const float4*)(x + (size_t)gn * IND + kc + col);
                float* d = &Xs[row * 33 + col];
                d[0] = vv.x; d[1] = vv.y; d[2] = vv.z; d[3] = vv.w;
            }
        }
        __syncthreads();
        if (n < NN) {
#pragma unroll
            for (int i = 0; i < 32; ++i) {
                float xv = Xs[tid * 33 + i];
                const float* wr = W1 + (size_t)(kc + i) * 16;   // wave-uniform -> s_load
#pragma unroll
                for (int j = 0; j < 16; ++j) acc[j] = fmaf(xv, wr[j], acc[j]);
            }
        }
    }
    if (n < NN) {
        float di = dinv[n];
#pragma unroll
        for (int j = 0; j < 16; j += 4)
            *(float4*)(h1s + (size_t)n * 16 + j) =
                make_float4(acc[j]*di, acc[j+1]*di, acc[j+2]*di, acc[j+3]*di);
    }
}

// ---------------- binned aggregation L1 + relu/b1 + W2 -> h2s (pre-scaled) ----------------
// one block per bucket; 32 groups x 16 lanes; batch-unroll 8
__global__ __launch_bounds__(512) void k_agg1(
    const unsigned int* __restrict__ boffs, const unsigned int* __restrict__ recs,
    const float* __restrict__ dinv, const float* __restrict__ h1s,
    const float* __restrict__ b1, const float* __restrict__ W2,
    float* __restrict__ h2s) {
    __shared__ float agg[NPB * 16];   // 16 KB
    __shared__ float dloc[NPB];
    const int b = blockIdx.x, tid = threadIdx.x;
    const int n0 = b * NPB;

    for (int i = tid; i < NPB; i += 512) dloc[i] = (n0 + i < NN) ? dinv[n0 + i] : 0.f;
    __syncthreads();
    for (int i = tid; i < NPB * 16; i += 512) {
        int ln = i >> 4, n = n0 + ln;
        float v = (n < NN) ? h1s[(size_t)n * 16 + (i & 15)] : 0.f;
        agg[i] = v * dloc[ln];          // self-loop: h1*dinv^2
    }
    __syncthreads();

    const unsigned int beg = boffs[b], end = boffs[b + 1];
    const int g = tid >> 4, j = tid & 15;
    unsigned int base = beg + g;
    // batched unroll-8: 8 independent rec loads, then 8 independent gathers
    while (base + 7u * 32u < end) {
        unsigned int r[8];
#pragma unroll
        for (int k = 0; k < 8; ++k) r[k] = recs[base + (unsigned)k * 32u];
        float v[8];
#pragma unroll
        for (int k = 0; k < 8; ++k) v[k] = h1s[(size_t)(r[k] & 0x1FFFFu) * 16 + j];
#pragma unroll
        for (int k = 0; k < 8; ++k) {
            unsigned int d = r[k] >> 17;
            unsafeAtomicAdd(&agg[d * 16 + j], v[k] * dloc[d]);
        }
        base += 8u * 32u;
    }
    for (; base < end; base += 32u) {
        unsigned int r = recs[base];
        unsigned int d = r >> 17;
        unsafeAtomicAdd(&agg[d * 16 + j], h1s[(size_t)(r & 0x1FFFFu) * 16 + j] * dloc[d]);
    }
    __syncthreads();

    for (int i = tid; i < NPB * 16; i += 512) agg[i] = fmaxf(agg[i] + b1[i & 15], 0.f);
    __syncthreads();
    for (int i = tid; i < NPB * 8; i += 512) {
        int ln = i >> 3, jj = i & 7, n = n0 + ln;
        if (n >= NN) continue;
        float o = 0.f;
        if (jj < 7) {
#pragma unroll
            for (int k = 0; k < 16; ++k) o = fmaf(agg[ln * 16 + k], W2[k * 7 + jj], o);
        }
        h2s[(size_t)n * 8 + jj] = o * dloc[ln];   // pre-scale by dinv[n]
    }
}

// ---------------- binned aggregation L2 + b2 + log_softmax -> out ----------------
// 64 groups x 8 lanes; batch-unroll 8
__global__ __launch_bounds__(512) void k_agg2(
    const unsigned int* __restrict__ boffs, const unsigned int* __restrict__ recs,
    const float* __restrict__ dinv, const float* __restrict__ h2s,
    const float* __restrict__ b2, float* __restrict__ out) {
    __shared__ float agg[NPB * 8];    // 8 KB
    __shared__ float dloc[NPB];
    const int b = blockIdx.x, tid = threadIdx.x;
    const int n0 = b * NPB;

    for (int i = tid; i < NPB; i += 512) dloc[i] = (n0 + i < NN) ? dinv[n0 + i] : 0.f;
    __syncthreads();
    for (int i = tid; i < NPB * 8; i += 512) {
        int ln = i >> 3, n = n0 + ln;
        float v = (n < NN) ? h2s[(size_t)n * 8 + (i & 7)] : 0.f;
        agg[i] = v * dloc[ln];          // self-loop: h2*dinv^2
    }
    __syncthreads();

    const unsigned int beg = boffs[b], end = boffs[b + 1];
    const int g = tid >> 3, j = tid & 7;
    unsigned int base = beg + g;
    while (base + 7u * 64u < end) {
        unsigned int r[8];
#pragma unroll
        for (int k = 0; k < 8; ++k) r[k] = recs[base + (unsigned)k * 64u];
        float v[8];
#pragma unroll
        for (int k = 0; k < 8; ++k) v[k] = h2s[(size_t)(r[k] & 0x1FFFFu) * 8 + j];
#pragma unroll
        for (int k = 0; k < 8; ++k) {
            unsigned int d = r[k] >> 17;
            unsafeAtomicAdd(&agg[d * 8 + j], v[k] * dloc[d]);
        }
        base += 8u * 64u;
    }
    for (; base < end; base += 64u) {
        unsigned int r = recs[base];
        unsigned int d = r >> 17;
        unsafeAtomicAdd(&agg[d * 8 + j], h2s[(size_t)(r & 0x1FFFFu) * 8 + j] * dloc[d]);
    }
    __syncthreads();

    for (int ln = tid; ln < NPB; ln += 512) {
        int n = n0 + ln;
        if (n >= NN) continue;
        float v[7]; float m = -1e30f;
#pragma unroll
        for (int jj = 0; jj < 7; ++jj) { v[jj] = agg[ln * 8 + jj] + b2[jj]; m = fmaxf(m, v[jj]); }
        float s = 0.f;
#pragma unroll
        for (int jj = 0; jj < 7; ++jj) s += expf(v[jj] - m);
        float ls = logf(s) + m;
#pragma unroll
        for (int jj = 0; jj < 7; ++jj) out[(size_t)n * 7 + jj] = v[jj] - ls;
    }
}

extern "C" void kernel_launch(void* const* d_in, const int* in_sizes, int n_in,
                              void* d_out, int out_size, void* d_ws, size_t ws_size,
                              hipStream_t stream) {
    const float* x  = (const float*)d_in[0];
    const int*   ei = (const int*)d_in[1];
    const float* W1 = (const float*)d_in[2];
    const float* b1 = (const float*)d_in[3];
    const float* W2 = (const float*)d_in[4];
    const float* b2 = (const float*)d_in[5];
    float* out = (float*)d_out;

    const int* src = ei;
    const int* dst = ei + NE;

    char* ws = (char*)d_ws;
    size_t o = 0;
    auto alloc = [&](size_t bytes) -> void* {
        void* p = ws + o;
        o = (o + bytes + 255) & ~(size_t)255;
        return p;
    };
    unsigned int* bcnt   = (unsigned int*)alloc((size_t)NBKT * 4);
    unsigned int* boffs  = (unsigned int*)alloc((size_t)(NBKT + 1) * 4);
    unsigned int* cursor = (unsigned int*)alloc((size_t)NBKT * 4);
    unsigned int* recs   = (unsigned int*)alloc((size_t)NE * 4);
    float*        dinv   = (float*)alloc((size_t)NN * 4);
    float*        h1s    = (float*)alloc((size_t)NN * 16 * 4);
    float*        h2s    = (float*)alloc((size_t)NN * 8 * 4);

    k_zero      <<<1, 512, 0, stream>>>(bcnt);
    k_hist      <<<512, 256, 0, stream>>>(dst, bcnt);
    k_scan      <<<1, 512, 0, stream>>>(bcnt, boffs, cursor);
    k_binscatter<<<NTILE, 512, 0, stream>>>(src, dst, cursor, recs);
    k_degbin    <<<NBKT, 256, 0, stream>>>(boffs, recs, dinv);
    k_gemm1     <<<NB_N, 256, 0, stream>>>(x, W1, dinv, h1s);
    k_agg1      <<<NBKT, 512, 0, stream>>>(boffs, recs, dinv, h1s, b1, W2, h2s);
    k_agg2      <<<NBKT, 512, 0, stream>>>(boffs, recs, dinv, h2s, b2, out);
}

// Round 5
// 871.192 us; speedup vs baseline: 1.0721x; 1.0692x over previous
//
#include <hip/hip_runtime.h>
#include <hip/hip_bf16.h>

#define NN   100000
#define NE   3200000
#define IND  512
#define NXCD 8
#define NB_N 391   // ceil(NN/256)

// ---- XCD id (measured working on gfx950: learn_hip m09) ----
__device__ __forceinline__ unsigned get_xcc() {
    unsigned x;
    asm volatile("s_getreg_b32 %0, hwreg(HW_REG_XCC_ID, 0, 4)" : "=s"(x));
    return x & 7u;
}

// ---- L2-resident atomics: no sc bits -> executes in local XCD's TCC ----
__device__ __forceinline__ void atomL2f(float* p, float v) {
    asm volatile("global_atomic_add_f32 %0, %1, off" :: "v"(p), "v"(v) : "memory");
}
__device__ __forceinline__ void atomL2u(unsigned* p, unsigned v) {
    asm volatile("global_atomic_add %0, %1, off" :: "v"(p), "v"(v) : "memory");
}
__device__ __forceinline__ void drain_vm() {
    asm volatile("s_waitcnt vmcnt(0)" ::: "memory");
}

// ---------------- zero the accumulator span (deg8|agg1c|agg2c) ----------------
__global__ __launch_bounds__(256) void k_zero(float4* __restrict__ p, int n4) {
    int stride = gridDim.x * 256;
    for (int i = blockIdx.x * 256 + threadIdx.x; i < n4; i += stride)
        p[i] = make_float4(0.f, 0.f, 0.f, 0.f);
}

// ---------------- degree: per-XCD int atomics ----------------
__global__ __launch_bounds__(256) void k_deg(const int* __restrict__ dst,
                                             unsigned* __restrict__ deg8) {
    unsigned* base = deg8 + (size_t)get_xcc() * NN;
    int e = blockIdx.x * 256 + threadIdx.x;
    if (e < NE) atomL2u(base + dst[e], 1u);
    drain_vm();
}

// ---------------- dinv = rsqrt(sum copies + 1) ----------------
__global__ __launch_bounds__(256) void k_dinv(const unsigned* __restrict__ deg8,
                                              float* __restrict__ dinv) {
    int n = blockIdx.x * 256 + threadIdx.x;
    if (n >= NN) return;
    unsigned d = 1u;
#pragma unroll
    for (int c = 0; c < NXCD; ++c) d += deg8[(size_t)c * NN + n];
    dinv[n] = rsqrtf((float)d);
}

// ---------------- layer-1 GEMM: h1s = (x @ W1) * dinv[n] ----------------
__global__ __launch_bounds__(256) void k_gemm1(
    const float* __restrict__ x, const float* __restrict__ W1,
    const float* __restrict__ dinv, float* __restrict__ h1s) {
    __shared__ float Xs[256 * 33];
    const int tid = threadIdx.x;
    const int n0  = blockIdx.x * 256;
    const int n   = n0 + tid;

    float acc[16];
#pragma unroll
    for (int j = 0; j < 16; ++j) acc[j] = 0.f;

    for (int kc = 0; kc < IND; kc += 32) {
        __syncthreads();
#pragma unroll
        for (int r = 0; r < 8; ++r) {
            int flat = r * 256 + tid;
            int row  = flat >> 3;
            int col  = (flat & 7) << 2;
            int gn   = n0 + row;
            if (gn < NN) {
                const float4 vv = *(const float4*)(x + (size_t)gn * IND + kc + col);
                float* d = &Xs[row * 33 + col];
                d[0] = vv.x; d[1] = vv.y; d[2] = vv.z; d[3] = vv.w;
            }
        }
        __syncthreads();
        if (n < NN) {
#pragma unroll
            for (int i = 0; i < 32; ++i) {
                float xv = Xs[tid * 33 + i];
                const float* wr = W1 + (size_t)(kc + i) * 16;   // wave-uniform -> s_load
#pragma unroll
                for (int j = 0; j < 16; ++j) acc[j] = fmaf(xv, wr[j], acc[j]);
            }
        }
    }
    if (n < NN) {
        float di = dinv[n];
#pragma unroll
        for (int j = 0; j < 16; j += 4)
            *(float4*)(h1s + (size_t)n * 16 + j) =
                make_float4(acc[j]*di, acc[j+1]*di, acc[j+2]*di, acc[j+3]*di);
    }
}

// ---------------- edge pass 1: agg1c[xcc][dst][j] += h1s[src][j] ----------------
// 16 lanes per edge; fire-and-forget L2-local atomics
__global__ __launch_bounds__(256) void k_edge1(
    const int* __restrict__ src, const int* __restrict__ dst,
    const float* __restrict__ h1s, float* __restrict__ agg1c) {
    float* base = agg1c + (size_t)get_xcc() * NN * 16;
    int gid = blockIdx.x * 256 + threadIdx.x;
    int e = gid >> 4;
    int j = gid & 15;
    if (e < NE) {
        int s = src[e], d = dst[e];
        atomL2f(base + (size_t)d * 16 + j, h1s[(size_t)s * 16 + j]);
    }
    drain_vm();
}

// ---------------- reduce 1: relu(dinv*(sum+self)+b1) @ W2 -> h2s (pre-scaled) ----------------
__global__ __launch_bounds__(256) void k_red1(
    const float* __restrict__ agg1c, const float* __restrict__ h1s,
    const float* __restrict__ dinv, const float* __restrict__ b1,
    const float* __restrict__ W2, float* __restrict__ h2s) {
    int n = blockIdx.x * 256 + threadIdx.x;
    if (n >= NN) return;
    float sum[16];
#pragma unroll
    for (int k = 0; k < 16; k += 4) {
        float4 v = *(const float4*)(h1s + (size_t)n * 16 + k);   // self-loop (pre-scaled)
        sum[k] = v.x; sum[k+1] = v.y; sum[k+2] = v.z; sum[k+3] = v.w;
    }
#pragma unroll
    for (int c = 0; c < NXCD; ++c) {
        const float* cp = agg1c + (size_t)c * NN * 16 + (size_t)n * 16;
#pragma unroll
        for (int k = 0; k < 16; k += 4) {
            float4 v = *(const float4*)(cp + k);
            sum[k] += v.x; sum[k+1] += v.y; sum[k+2] += v.z; sum[k+3] += v.w;
        }
    }
    float di = dinv[n];
    float z[16];
#pragma unroll
    for (int k = 0; k < 16; ++k) z[k] = fmaxf(sum[k] * di + b1[k], 0.f);
    float o[8];
#pragma unroll
    for (int jj = 0; jj < 7; ++jj) {
        float a = 0.f;
#pragma unroll
        for (int k = 0; k < 16; ++k) a = fmaf(z[k], W2[k * 7 + jj], a);
        o[jj] = a * di;                   // pre-scale by dinv[n] for layer-2 edges
    }
    o[7] = 0.f;
    *(float4*)(h2s + (size_t)n * 8 + 0) = make_float4(o[0], o[1], o[2], o[3]);
    *(float4*)(h2s + (size_t)n * 8 + 4) = make_float4(o[4], o[5], o[6], o[7]);
}

// ---------------- edge pass 2: agg2c[xcc][dst][j] += h2s[src][j], j<7 ----------------
__global__ __launch_bounds__(256) void k_edge2(
    const int* __restrict__ src, const int* __restrict__ dst,
    const float* __restrict__ h2s, float* __restrict__ agg2c) {
    float* base = agg2c + (size_t)get_xcc() * NN * 8;
    int gid = blockIdx.x * 256 + threadIdx.x;
    int e = gid >> 3;
    int j = gid & 7;
    if (e < NE && j < 7) {
        int s = src[e], d = dst[e];
        atomL2f(base + (size_t)d * 8 + j, h2s[(size_t)s * 8 + j]);
    }
    drain_vm();
}

// ---------------- reduce 2: dinv*(sum+self)+b2 -> log_softmax -> out ----------------
__global__ __launch_bounds__(256) void k_red2(
    const float* __restrict__ agg2c, const float* __restrict__ h2s,
    const float* __restrict__ dinv, const float* __restrict__ b2,
    float* __restrict__ out) {
    int n = blockIdx.x * 256 + threadIdx.x;
    if (n >= NN) return;
    float sum[7];
#pragma unroll
    for (int j = 0; j < 7; ++j) sum[j] = h2s[(size_t)n * 8 + j];  // self (pre-scaled)
#pragma unroll
    for (int c = 0; c < NXCD; ++c) {
        const float* cp = agg2c + (size_t)c * NN * 8 + (size_t)n * 8;
#pragma unroll
        for (int j = 0; j < 7; ++j) sum[j] += cp[j];
    }
    float di = dinv[n];
    float v[7]; float m = -1e30f;
#pragma unroll
    for (int j = 0; j < 7; ++j) { v[j] = sum[j] * di + b2[j]; m = fmaxf(m, v[j]); }
    float s = 0.f;
#pragma unroll
    for (int j = 0; j < 7; ++j) s += expf(v[j] - m);
    float ls = logf(s) + m;
#pragma unroll
    for (int j = 0; j < 7; ++j) out[(size_t)n * 7 + j] = v[j] - ls;
}

extern "C" void kernel_launch(void* const* d_in, const int* in_sizes, int n_in,
                              void* d_out, int out_size, void* d_ws, size_t ws_size,
                              hipStream_t stream) {
    const float* x  = (const float*)d_in[0];
    const int*   ei = (const int*)d_in[1];
    const float* W1 = (const float*)d_in[2];
    const float* b1 = (const float*)d_in[3];
    const float* W2 = (const float*)d_in[4];
    const float* b2 = (const float*)d_in[5];
    float* out = (float*)d_out;

    const int* src = ei;
    const int* dst = ei + NE;

    char* ws = (char*)d_ws;
    size_t o = 0;
    auto alloc = [&](size_t bytes) -> void* {
        void* p = ws + o;
        o = (o + bytes + 255) & ~(size_t)255;
        return p;
    };
    // contiguous atomic-accumulator span (zeroed in one pass)
    unsigned* deg8  = (unsigned*)alloc((size_t)NXCD * NN * 4);        // 3.2 MB
    float*    agg1c = (float*)alloc((size_t)NXCD * NN * 16 * 4);      // 51.2 MB
    float*    agg2c = (float*)alloc((size_t)NXCD * NN * 8 * 4);       // 25.6 MB
    float*    dinv  = (float*)alloc((size_t)NN * 4);
    float*    h1s   = (float*)alloc((size_t)NN * 16 * 4);
    float*    h2s   = (float*)alloc((size_t)NN * 8 * 4);

    const size_t zero_bytes = (size_t)NXCD * NN * (4 + 64 + 32);
    const int n4 = (int)(zero_bytes / 16);

    k_zero  <<<4096, 256, 0, stream>>>((float4*)deg8, n4);
    k_deg   <<<(NE + 255) / 256, 256, 0, stream>>>(dst, deg8);
    k_dinv  <<<NB_N, 256, 0, stream>>>(deg8, dinv);
    k_gemm1 <<<NB_N, 256, 0, stream>>>(x, W1, dinv, h1s);
    k_edge1 <<<(int)(((size_t)NE * 16 + 255) / 256), 256, 0, stream>>>(src, dst, h1s, agg1c);
    k_red1  <<<NB_N, 256, 0, stream>>>(agg1c, h1s, dinv, b1, W2, h2s);
    k_edge2 <<<(int)(((size_t)NE * 8 + 255) / 256), 256, 0, stream>>>(src, dst, h2s, agg2c);
    k_red2  <<<NB_N, 256, 0, stream>>>(agg2c, h2s, dinv, b2, out);
}